// Round 3
// baseline (450.952 us; speedup 1.0000x reference)
//
#include <hip/hip_runtime.h>
#include <hip/hip_bf16.h>

#define B_  8
#define NQ_ 2048
#define SK_ 2048
#define D_  128
#define QT  64          // Q rows per block (16 per wave)
#define KT  64          // K/V tile
#define NROWS (B_ * NQ_)            // 16384 global q-rows
#define SPLITS 3                    // k-splits: 11/11/10 tiles of 32
#define ML_OFF ((size_t)SPLITS * NROWS * D_)   // float offset of (m,l) table in ws

typedef __attribute__((ext_vector_type(8))) short bf16x8;
typedef __attribute__((ext_vector_type(4))) float f32x4;

// fp32 -> bf16 round-to-nearest-even
__device__ __forceinline__ unsigned short f2bf(float f) {
    union { float f; unsigned u; } v; v.f = f;
    unsigned r = v.u + 0x7fffu + ((v.u >> 16) & 1u);
    return (unsigned short)(r >> 16);
}

// ---------------- pass 1: per-split flash attention, unnormalized ----------------
__global__ __launch_bounds__(256, 3)
void sdpa_p1(const float* __restrict__ Q, const float* __restrict__ K,
             const float* __restrict__ V, const int* __restrict__ M,
             const float* __restrict__ W, float* __restrict__ ws)
{
    const int b     = blockIdx.x & 7;        // batch == XCD id -> K/V stays in one L2
    const int rest  = blockIdx.x >> 3;       // 0..95
    const int qb    = rest & 31;
    const int ks    = rest >> 5;             // 0..2
    const int qbase = qb * QT;
    const int t0    = ks * 11;               // first k-tile of this split
    const int ntl   = (ks < 2) ? 11 : 10;    // tiles in this split (11+11+10=32)

    __shared__ unsigned short Ks[KT][D_ + 8];   // K tile, natural [k][d]
    __shared__ unsigned short Vt[D_][KT + 8];   // V tile, transposed [d][k]
    __shared__ unsigned short Ss[QT][KT + 8];   // P tile (C-layout -> A-layout)

    const int tid  = threadIdx.x;
    const int wv   = tid >> 6;
    const int lane = tid & 63;
    const int quad = lane >> 4;
    const int lq   = lane & 15;
    const int c4s  = (tid & 31) * 4;   // staging d-offset

    // ---- persistent Q A-fragments ----
    bf16x8 qf[4];
    {
        const float* qp = Q + ((size_t)b * NQ_ + qbase + wv * 16 + lq) * D_;
        #pragma unroll
        for (int t = 0; t < 4; ++t) {
            float4 a0 = *(const float4*)(qp + t * 32 + quad * 8);
            float4 a1 = *(const float4*)(qp + t * 32 + quad * 8 + 4);
            qf[t][0] = (short)f2bf(a0.x); qf[t][1] = (short)f2bf(a0.y);
            qf[t][2] = (short)f2bf(a0.z); qf[t][3] = (short)f2bf(a0.w);
            qf[t][4] = (short)f2bf(a1.x); qf[t][5] = (short)f2bf(a1.y);
            qf[t][6] = (short)f2bf(a1.z); qf[t][7] = (short)f2bf(a1.w);
        }
    }

    float m2[4], l[4];
    #pragma unroll
    for (int r = 0; r < 4; ++r) { m2[r] = -INFINITY; l[r] = 0.f; }
    f32x4 o[8];
    #pragma unroll
    for (int c = 0; c < 8; ++c) o[c] = (f32x4){0.f, 0.f, 0.f, 0.f};

    const float SCL = 0.08838834764831845f * 1.44269504088896f; // 1/sqrt(128)*log2e

    float    wr[4][4];
    unsigned mpack[4];
    const float* wp  = W + ((size_t)b * NQ_ + qbase + wv * 16 + quad * 4) * SK_ + lq;
    const int*   mp_ = M + ((size_t)b * NQ_ + qbase + wv * 16 + quad * 4) * SK_ + lq;
    auto load_wm = [&](int kb_el) {
        #pragma unroll
        for (int r = 0; r < 4; ++r) {
            unsigned mp = 0;
            #pragma unroll
            for (int c = 0; c < 4; ++c) {
                size_t idx = (size_t)r * SK_ + kb_el + c * 16;
                wr[r][c] = wp[idx];
                mp |= (mp_[idx] != 0 ? 1u : 0u) << c;
            }
            mpack[r] = mp;
        }
    };

    float4 kr[8], vr[8];
    auto load_kv = [&](int kb_el) {
        const float* kp = K + ((size_t)b * SK_ + kb_el) * D_ + c4s;
        const float* vp = V + ((size_t)b * SK_ + kb_el) * D_ + c4s;
        #pragma unroll
        for (int p = 0; p < 2; ++p) {
            int k4 = ((tid >> 5) + p * 8) * 4;
            #pragma unroll
            for (int i = 0; i < 4; ++i) {
                kr[p * 4 + i] = *(const float4*)(kp + (size_t)(k4 + i) * D_);
                vr[p * 4 + i] = *(const float4*)(vp + (size_t)(k4 + i) * D_);
            }
        }
    };

    load_kv(t0 * KT);
    load_wm(t0 * KT);

    #pragma unroll 1
    for (int kt = 0; kt < ntl; ++kt) {
        // ---- stage prefetched K/V regs -> LDS (bf16; V transposed) ----
        #pragma unroll
        for (int p = 0; p < 2; ++p) {
            int k4 = ((tid >> 5) + p * 8) * 4;
            #pragma unroll
            for (int i = 0; i < 4; ++i) {
                float4 kv = kr[p * 4 + i];
                *(ushort4*)&Ks[k4 + i][c4s] =
                    make_ushort4(f2bf(kv.x), f2bf(kv.y), f2bf(kv.z), f2bf(kv.w));
            }
            float4 v0 = vr[p * 4 + 0], v1 = vr[p * 4 + 1];
            float4 v2 = vr[p * 4 + 2], v3 = vr[p * 4 + 3];
            *(ushort4*)&Vt[c4s + 0][k4] = make_ushort4(f2bf(v0.x), f2bf(v1.x), f2bf(v2.x), f2bf(v3.x));
            *(ushort4*)&Vt[c4s + 1][k4] = make_ushort4(f2bf(v0.y), f2bf(v1.y), f2bf(v2.y), f2bf(v3.y));
            *(ushort4*)&Vt[c4s + 2][k4] = make_ushort4(f2bf(v0.z), f2bf(v1.z), f2bf(v2.z), f2bf(v3.z));
            *(ushort4*)&Vt[c4s + 3][k4] = make_ushort4(f2bf(v0.w), f2bf(v1.w), f2bf(v2.w), f2bf(v3.w));
        }
        if (kt + 1 < ntl) load_kv((t0 + kt + 1) * KT);
        __syncthreads();

        // ---- S = Q Kt^T ----
        f32x4 s[4];
        #pragma unroll
        for (int c = 0; c < 4; ++c) s[c] = (f32x4){0.f, 0.f, 0.f, 0.f};
        #pragma unroll
        for (int t = 0; t < 4; ++t) {
            #pragma unroll
            for (int c = 0; c < 4; ++c) {
                bf16x8 kf = *(const bf16x8*)&Ks[c * 16 + lq][t * 32 + quad * 8];
                s[c] = __builtin_amdgcn_mfma_f32_16x16x32_bf16(qf[t], kf, s[c], 0, 0, 0);
            }
        }

        // ---- logits (log2 domain) ----
        float lg[4][4];
        #pragma unroll
        for (int r = 0; r < 4; ++r)
            #pragma unroll
            for (int c = 0; c < 4; ++c) {
                float val = s[c][r] * (SCL * wr[r][c]);
                lg[r][c] = ((mpack[r] >> c) & 1u) ? -INFINITY : val;
            }
        if (kt + 1 < ntl) load_wm((t0 + kt + 1) * KT);

        // ---- online softmax ----
        float alpha[4], p[4][4];
        #pragma unroll
        for (int r = 0; r < 4; ++r) {
            float tm = fmaxf(fmaxf(lg[r][0], lg[r][1]), fmaxf(lg[r][2], lg[r][3]));
            tm = fmaxf(tm, __shfl_xor(tm, 1));
            tm = fmaxf(tm, __shfl_xor(tm, 2));
            tm = fmaxf(tm, __shfl_xor(tm, 4));
            tm = fmaxf(tm, __shfl_xor(tm, 8));
            float mn = fmaxf(m2[r], tm);
            float ms = (mn == -INFINITY) ? 0.f : mn;
            float a  = exp2f(m2[r] - ms);
            alpha[r] = a;
            float rs = 0.f;
            #pragma unroll
            for (int c = 0; c < 4; ++c) {
                float pv = exp2f(lg[r][c] - ms);
                p[r][c] = pv;
                rs += pv;
            }
            rs += __shfl_xor(rs, 1);
            rs += __shfl_xor(rs, 2);
            rs += __shfl_xor(rs, 4);
            rs += __shfl_xor(rs, 8);
            l[r]  = l[r] * a + rs;
            m2[r] = mn;
        }
        #pragma unroll
        for (int c = 0; c < 8; ++c)
            #pragma unroll
            for (int r = 0; r < 4; ++r)
                o[c][r] *= alpha[r];

        // ---- P: C-layout -> LDS -> A-layout (own rows only, same-wave RAW) ----
        #pragma unroll
        for (int r = 0; r < 4; ++r)
            #pragma unroll
            for (int c = 0; c < 4; ++c)
                Ss[wv * 16 + quad * 4 + r][c * 16 + lq] = f2bf(p[r][c]);

        // ---- O += P Vt ----
        #pragma unroll
        for (int t = 0; t < 2; ++t) {
            bf16x8 af = *(const bf16x8*)&Ss[wv * 16 + lq][t * 32 + quad * 8];
            #pragma unroll
            for (int c = 0; c < 8; ++c) {
                bf16x8 vf = *(const bf16x8*)&Vt[c * 16 + lq][t * 32 + quad * 8];
                o[c] = __builtin_amdgcn_mfma_f32_16x16x32_bf16(af, vf, o[c], 0, 0, 0);
            }
        }
        __syncthreads();
    }

    // ---- epilogue: unnormalized partials + (m,l) to workspace ----
    #pragma unroll
    for (int r = 0; r < 4; ++r) {
        const int gq = b * NQ_ + qbase + wv * 16 + quad * 4 + r;
        float* op = ws + ((size_t)ks * NROWS + gq) * D_;
        #pragma unroll
        for (int c = 0; c < 8; ++c)
            op[c * 16 + lq] = o[c][r];
        if (lq == 0) {
            float* mlp = ws + ML_OFF + ((size_t)ks * NROWS + gq) * 2;
            mlp[0] = m2[r];
            mlp[1] = l[r];
        }
    }
}

// ---------------- pass 2: combine splits ----------------
__global__ __launch_bounds__(256)
void sdpa_p2(const float* __restrict__ ws, float* __restrict__ O)
{
    const int w    = threadIdx.x >> 6;
    const int lane = threadIdx.x & 63;
    const int row  = blockIdx.x * 4 + w;           // 0..16383
    const float* mlp = ws + ML_OFF;

    float m0 = mlp[((size_t)0 * NROWS + row) * 2], l0 = mlp[((size_t)0 * NROWS + row) * 2 + 1];
    float m1 = mlp[((size_t)1 * NROWS + row) * 2], l1 = mlp[((size_t)1 * NROWS + row) * 2 + 1];
    float m2 = mlp[((size_t)2 * NROWS + row) * 2], l2 = mlp[((size_t)2 * NROWS + row) * 2 + 1];

    float ms = fmaxf(fmaxf(m0, m1), m2);
    float2* out = (float2*)(O + (size_t)row * D_) + lane;
    if (ms == -INFINITY) { *out = make_float2(0.f, 0.f); return; }

    float a0 = exp2f(m0 - ms), a1 = exp2f(m1 - ms), a2 = exp2f(m2 - ms);
    float ls = a0 * l0 + a1 * l1 + a2 * l2;
    float inv = (ls > 0.f) ? 1.0f / ls : 0.f;

    const float2* p0 = (const float2*)(ws + ((size_t)0 * NROWS + row) * D_) + lane;
    const float2* p1 = (const float2*)(ws + ((size_t)1 * NROWS + row) * D_) + lane;
    const float2* p2 = (const float2*)(ws + ((size_t)2 * NROWS + row) * D_) + lane;
    float2 v0 = *p0, v1 = *p1, v2 = *p2;
    float2 res;
    res.x = (a0 * v0.x + a1 * v1.x + a2 * v2.x) * inv;
    res.y = (a0 * v0.y + a1 * v1.y + a2 * v2.y) * inv;
    *out = res;
}

extern "C" void kernel_launch(void* const* d_in, const int* in_sizes, int n_in,
                              void* d_out, int out_size, void* d_ws, size_t ws_size,
                              hipStream_t stream) {
    const float* Q = (const float*)d_in[0];
    const float* K = (const float*)d_in[1];
    const float* V = (const float*)d_in[2];
    const int*   M = (const int*)d_in[3];    // bool mask uploaded as int32
    const float* W = (const float*)d_in[4];
    float*       O = (float*)d_out;
    float*       S = (float*)d_ws;           // needs SPLITS*(NROWS*D_ + NROWS*2)*4 = 25.7 MB

    sdpa_p1<<<dim3(B_ * 32 * SPLITS), 256, 0, stream>>>(Q, K, V, M, W, S);
    sdpa_p2<<<dim3(NROWS / 4), 256, 0, stream>>>(S, O);
}

// Round 4
// 385.432 us; speedup vs baseline: 1.1700x; 1.1700x over previous
//
#include <hip/hip_runtime.h>

#define B_  8
#define NQ_ 2048
#define SK_ 2048
#define D_  128
#define KT  64
#define NT  (SK_ / KT)

typedef __attribute__((ext_vector_type(8))) short bf16x8;
typedef __attribute__((ext_vector_type(4))) float f32x4;

// fp32 -> bf16 round-to-nearest-even
__device__ __forceinline__ unsigned short f2bf(float f) {
    union { float f; unsigned u; } v; v.f = f;
    unsigned r = v.u + 0x7fffu + ((v.u >> 16) & 1u);
    return (unsigned short)(r >> 16);
}
__device__ __forceinline__ ushort4 f2bf4(float4 a) {
    return make_ushort4(f2bf(a.x), f2bf(a.y), f2bf(a.z), f2bf(a.w));
}

// ---- prepass: Kb = bf16(K) same layout; Vtb = bf16(V) transposed [b][d][k] ----
// K/V bf16 per batch = 512 KB each -> L2-resident per XCD afterwards.
__global__ __launch_bounds__(256)
void prep(const float* __restrict__ K, const float* __restrict__ V,
          unsigned short* __restrict__ Kb, unsigned short* __restrict__ Vtb)
{
    const int b  = blockIdx.x & 7;       // batch == XCD (heuristic pin)
    const int r0 = (blockIdx.x >> 3) * 64;
    const int tid = threadIdx.x;
    const int row = tid >> 2, seg = tid & 3;
    __shared__ unsigned short Vs[64][136];   // +8 pad

    {
        const size_t base = ((size_t)(b * SK_ + r0 + row)) * D_ + seg * 32;
        const float4* kp  = (const float4*)(K + base);
        const float4* vp  = (const float4*)(V + base);
        ushort4*      kbp = (ushort4*)(Kb + base);
        #pragma unroll
        for (int j = 0; j < 8; ++j) {
            kbp[j] = f2bf4(kp[j]);
            *(ushort4*)&Vs[row][seg * 32 + j * 4] = f2bf4(vp[j]);
        }
    }
    __syncthreads();
    const int d = tid >> 1, hf = tid & 1;
    ushort4* op = (ushort4*)(Vtb + ((size_t)(b * D_ + d)) * SK_ + r0 + hf * 32);
    #pragma unroll
    for (int j = 0; j < 8; ++j) {
        ushort4 t;
        t.x = Vs[hf * 32 + j * 4 + 0][d];
        t.y = Vs[hf * 32 + j * 4 + 1][d];
        t.z = Vs[hf * 32 + j * 4 + 2][d];
        t.w = Vs[hf * 32 + j * 4 + 3][d];
        op[j] = t;
    }
}

// ---- main: barrier-free flash attention; 2 waves/block, 16 q-rows/wave ----
// All K/Vt fragments load directly from L2-resident bf16 tensors (16 B/lane,
// exact MFMA fragment shape). Only LDS use: wave-private P C->A round-trip.
__global__ __launch_bounds__(128)
void sdpa_fwd(const float* __restrict__ Q, const unsigned short* __restrict__ Kb,
              const unsigned short* __restrict__ Vtb, const int* __restrict__ M,
              const float* __restrict__ W, float* __restrict__ O)
{
    const int b  = blockIdx.x & 7;           // batch == XCD -> Kb/Vtb stay in L2
    const int qb = blockIdx.x >> 3;          // 0..63
    const int tid  = threadIdx.x;
    const int wv   = tid >> 6;
    const int lane = tid & 63;
    const int quad = lane >> 4;
    const int lq   = lane & 15;
    const int q0   = qb * 32 + wv * 16;      // this wave's q-row base

    __shared__ unsigned short Ss[2][16][72]; // per-wave P round-trip (+8 pad)

    // ---- persistent Q A-fragments (rows q0+lq) ----
    bf16x8 qf[4];
    {
        const float* qp = Q + ((size_t)(b * NQ_ + q0 + lq)) * D_;
        #pragma unroll
        for (int t = 0; t < 4; ++t) {
            float4 a0 = *(const float4*)(qp + t * 32 + quad * 8);
            float4 a1 = *(const float4*)(qp + t * 32 + quad * 8 + 4);
            qf[t][0] = (short)f2bf(a0.x); qf[t][1] = (short)f2bf(a0.y);
            qf[t][2] = (short)f2bf(a0.z); qf[t][3] = (short)f2bf(a0.w);
            qf[t][4] = (short)f2bf(a1.x); qf[t][5] = (short)f2bf(a1.y);
            qf[t][6] = (short)f2bf(a1.z); qf[t][7] = (short)f2bf(a1.w);
        }
    }

    float m2[4], l[4];
    #pragma unroll
    for (int r = 0; r < 4; ++r) { m2[r] = -INFINITY; l[r] = 0.f; }
    f32x4 o[8];
    #pragma unroll
    for (int c = 0; c < 8; ++c) o[c] = (f32x4){0.f, 0.f, 0.f, 0.f};

    const float SCL = 0.08838834764831845f * 1.44269504088896f; // 1/sqrt(128)*log2e

    // W/mask stream (the HBM driver). Loaded one tile ahead; no barriers exist
    // to drain these, so they stay in flight across the whole iteration.
    float    wr[4][4];
    unsigned mpack[4];
    const float* wp  = W + ((size_t)(b * NQ_ + q0 + quad * 4)) * SK_ + lq;
    const int*   mp_ = M + ((size_t)(b * NQ_ + q0 + quad * 4)) * SK_ + lq;
    auto load_wm = [&](int kb_el) {
        #pragma unroll
        for (int r = 0; r < 4; ++r) {
            unsigned mp = 0;
            #pragma unroll
            for (int c = 0; c < 4; ++c) {
                size_t idx = (size_t)r * SK_ + kb_el + c * 16;
                wr[r][c] = wp[idx];
                mp |= (mp_[idx] != 0 ? 1u : 0u) << c;
            }
            mpack[r] = mp;
        }
    };
    load_wm(0);

    const unsigned short* kbase = Kb  + (size_t)b * SK_ * D_ + lq * (size_t)D_ + quad * 8;
    const unsigned short* vbase = Vtb + (size_t)b * D_ * SK_ + lq * (size_t)SK_ + quad * 8;

    #pragma unroll 1
    for (int kt = 0; kt < NT; ++kt) {
        const int kb = kt * KT;

        // ---- S = Q Kt^T : K B-fragments direct from global (L2) ----
        f32x4 s[4];
        #pragma unroll
        for (int c = 0; c < 4; ++c) s[c] = (f32x4){0.f, 0.f, 0.f, 0.f};
        #pragma unroll
        for (int t = 0; t < 4; ++t) {
            bf16x8 kf[4];
            #pragma unroll
            for (int c = 0; c < 4; ++c)
                kf[c] = *(const bf16x8*)(kbase + (size_t)(kb + c * 16) * D_ + t * 32);
            #pragma unroll
            for (int c = 0; c < 4; ++c)
                s[c] = __builtin_amdgcn_mfma_f32_16x16x32_bf16(qf[t], kf[c], s[c], 0, 0, 0);
        }

        // ---- logits (log2 domain) ----
        float lg[4][4];
        #pragma unroll
        for (int r = 0; r < 4; ++r)
            #pragma unroll
            for (int c = 0; c < 4; ++c) {
                float val = s[c][r] * (SCL * wr[r][c]);
                lg[r][c] = ((mpack[r] >> c) & 1u) ? -INFINITY : val;
            }
        if (kt + 1 < NT) load_wm(kb + KT);   // issue next W/M; in flight all iter

        // ---- online softmax ----
        float alpha[4], p[4][4];
        #pragma unroll
        for (int r = 0; r < 4; ++r) {
            float tm = fmaxf(fmaxf(lg[r][0], lg[r][1]), fmaxf(lg[r][2], lg[r][3]));
            tm = fmaxf(tm, __shfl_xor(tm, 1));
            tm = fmaxf(tm, __shfl_xor(tm, 2));
            tm = fmaxf(tm, __shfl_xor(tm, 4));
            tm = fmaxf(tm, __shfl_xor(tm, 8));
            float mn = fmaxf(m2[r], tm);
            float ms = (mn == -INFINITY) ? 0.f : mn;
            float a  = exp2f(m2[r] - ms);
            alpha[r] = a;
            float rs = 0.f;
            #pragma unroll
            for (int c = 0; c < 4; ++c) {
                float pv = exp2f(lg[r][c] - ms);
                p[r][c] = pv;
                rs += pv;
            }
            rs += __shfl_xor(rs, 1);
            rs += __shfl_xor(rs, 2);
            rs += __shfl_xor(rs, 4);
            rs += __shfl_xor(rs, 8);
            l[r]  = l[r] * a + rs;
            m2[r] = mn;
        }
        #pragma unroll
        for (int c = 0; c < 8; ++c)
            #pragma unroll
            for (int r = 0; r < 4; ++r)
                o[c][r] *= alpha[r];

        // ---- P: C-layout -> LDS -> A-layout (wave-private; same-wave RAW) ----
        #pragma unroll
        for (int r = 0; r < 4; ++r)
            #pragma unroll
            for (int c = 0; c < 4; ++c)
                Ss[wv][quad * 4 + r][c * 16 + lq] = f2bf(p[r][c]);

        // ---- O += P Vt : V B-fragments direct from global (L2) ----
        #pragma unroll
        for (int t = 0; t < 2; ++t) {
            bf16x8 af = *(const bf16x8*)&Ss[wv][lq][t * 32 + quad * 8];
            #pragma unroll
            for (int c = 0; c < 8; ++c) {
                bf16x8 vf = *(const bf16x8*)(vbase + (size_t)(c * 16) * SK_ + kb + t * 32);
                o[c] = __builtin_amdgcn_mfma_f32_16x16x32_bf16(af, vf, o[c], 0, 0, 0);
            }
        }
    }

    // ---- epilogue: O / l ----
    #pragma unroll
    for (int r = 0; r < 4; ++r) {
        float li = 1.0f / l[r];
        float* op = O + ((size_t)(b * NQ_ + q0 + quad * 4 + r)) * D_;
        #pragma unroll
        for (int c = 0; c < 8; ++c)
            op[c * 16 + lq] = o[c][r] * li;
    }
}

extern "C" void kernel_launch(void* const* d_in, const int* in_sizes, int n_in,
                              void* d_out, int out_size, void* d_ws, size_t ws_size,
                              hipStream_t stream) {
    const float* Q = (const float*)d_in[0];
    const float* K = (const float*)d_in[1];
    const float* V = (const float*)d_in[2];
    const int*   M = (const int*)d_in[3];    // bool mask uploaded as int32
    const float* W = (const float*)d_in[4];
    float*       O = (float*)d_out;

    unsigned short* Kb  = (unsigned short*)d_ws;                    // 4.2 MB
    unsigned short* Vtb = Kb + (size_t)B_ * SK_ * D_;               // 4.2 MB

    prep<<<dim3(B_ * (SK_ / 64)), 256, 0, stream>>>(K, V, Kb, Vtb);
    sdpa_fwd<<<dim3(B_ * (NQ_ / 32)), 128, 0, stream>>>(Q, Kb, Vtb, M, W, O);
}